// Round 11
// baseline (792.580 us; speedup 1.0000x reference)
//
#include <hip/hip_runtime.h>
#include <hip/hip_bf16.h>
#include <math.h>

// B=8, S=512, HID=512, HEADS=8, DH=64, FF=768, NL=3, SPAN=256, MAXP=512, VOCAB=100
#define EPS_LN 1e-7f
#define INV_SCALE 0.072168783648703221f   // 1/sqrt(64*3)
#define NEGMAX -3.402823466e38f

typedef unsigned short u16;
typedef __attribute__((ext_vector_type(8))) short bf16x8;  // 8 bf16 = 4 VGPRs
typedef __attribute__((ext_vector_type(4))) float f32x4;

__device__ __forceinline__ u16 f2b(float f) {
  union { float f; unsigned int u; } v; v.f = f;
  unsigned int r = v.u + 0x7FFFu + ((v.u >> 16) & 1u);
  return (u16)(r >> 16);
}
__device__ __forceinline__ float b2f(u16 u) {
  union { unsigned int u; float f; } v; v.u = ((unsigned int)u) << 16;
  return v.f;
}
__device__ __forceinline__ float gelu_exact(float v) {
  return 0.5f * v * (1.f + erff(v * 0.70710678118654752440f));
}
// DeBERTa log-bucket for a single rel value (bit-exact with table build)
__device__ __forceinline__ int bucket_clip(int rel) {
  int a = (rel < 128 && rel > -128) ? 127 : (rel < 0 ? -rel : rel);
  int bucket;
  if (a <= 128) {
    bucket = rel;
  } else {
    double lp = ceil(log((double)a / 128.0) / log(511.0 / 128.0) * 127.0) + 128.0;
    int l = (int)lp;
    bucket = (rel > 0) ? l : -l;
  }
  int c = bucket + 256;
  return c < 0 ? 0 : (c > 511 ? 511 : c);
}

// ---------------------------------------------------------------------------
// Small tables: crel (1023) + concat bias [3][1536] = bq|bk|bv.
// ---------------------------------------------------------------------------
__global__ __launch_bounds__(256) void tables_kernel(const float* __restrict__ bq,
                                                     const float* __restrict__ bk,
                                                     const float* __restrict__ bv,
                                                     int* __restrict__ crel,
                                                     float* __restrict__ bqkv) {
  int i = blockIdx.x * 256 + threadIdx.x;
  if (i < 1023) crel[i] = bucket_clip(i - 511);
  int j = i - 1024;
  if (j >= 0 && j < 4608) {
    int l = j / 1536, c = j - l * 1536;
    float v = (c < 512) ? bq[l * 512 + c]
                        : (c < 1024) ? bk[l * 512 + c - 512] : bv[l * 512 + c - 1024];
    bqkv[j] = v;
  }
}

// ---------------------------------------------------------------------------
// LayerNorm over 512 cols; writes fp32 master and optional bf16 mirror.
// ---------------------------------------------------------------------------
template <bool RESID, bool MASK>
__global__ __launch_bounds__(256) void ln_kernel(const float* __restrict__ x,
                                                 const float* __restrict__ res,
                                                 const float* __restrict__ gam,
                                                 const float* __restrict__ bet,
                                                 const float* __restrict__ mask,
                                                 float* __restrict__ out,
                                                 u16* __restrict__ outb, int nrows) {
  int w = threadIdx.x >> 6, ln = threadIdx.x & 63;
  int row = blockIdx.x * 4 + w;
  if (row >= nrows) return;
  const float* xr = x + (size_t)row * 512;
  float v[8];
#pragma unroll
  for (int c = 0; c < 2; ++c) {
    float4 a = *(const float4*)(xr + (ln << 3) + (c << 2));
    v[c * 4 + 0] = a.x; v[c * 4 + 1] = a.y; v[c * 4 + 2] = a.z; v[c * 4 + 3] = a.w;
    if (RESID) {
      float4 r4 = *(const float4*)(res + (size_t)row * 512 + (ln << 3) + (c << 2));
      v[c * 4 + 0] += r4.x; v[c * 4 + 1] += r4.y; v[c * 4 + 2] += r4.z; v[c * 4 + 3] += r4.w;
    }
  }
  float sum = 0.f;
#pragma unroll
  for (int c = 0; c < 8; ++c) sum += v[c];
#pragma unroll
  for (int off = 32; off; off >>= 1) sum += __shfl_xor(sum, off);
  float mu = sum * (1.f / 512.f);
  float vs = 0.f;
#pragma unroll
  for (int c = 0; c < 8; ++c) { float d = v[c] - mu; vs += d * d; }
#pragma unroll
  for (int off = 32; off; off >>= 1) vs += __shfl_xor(vs, off);
  float rstd = 1.f / sqrtf(vs * (1.f / 512.f) + EPS_LN);
  float mk = MASK ? mask[row] : 1.f;
  float* orow = out + (size_t)row * 512;
  u16* brow = outb ? outb + (size_t)row * 512 : nullptr;
#pragma unroll
  for (int c = 0; c < 2; ++c) {
    int col = (ln << 3) + (c << 2);
    float o[4];
#pragma unroll
    for (int q = 0; q < 4; ++q)
      o[q] = ((v[c * 4 + q] - mu) * rstd * gam[col + q] + bet[col + q]) * mk;
    *(float4*)(orow + col) = make_float4(o[0], o[1], o[2], o[3]);
    if (brow) {
      ushort4 ob = { f2b(o[0]), f2b(o[1]), f2b(o[2]), f2b(o[3]) };
      *(ushort4*)(brow + col) = ob;
    }
  }
}

// ---------------------------------------------------------------------------
// ALL weight transposes (f32 [K][N] -> bf16 [N][K]) in ONE dispatch.
// job = blockIdx.z: 0-8 QKV(l,part), 9-11 O, 12-14 I, 15-17 F, 18 C.
// ---------------------------------------------------------------------------
__global__ __launch_bounds__(256) void wtrans_all(const float* __restrict__ Wq,
                                                  const float* __restrict__ Wk,
                                                  const float* __restrict__ Wv,
                                                  const float* __restrict__ Wo,
                                                  const float* __restrict__ Wi,
                                                  const float* __restrict__ Wf,
                                                  const float* __restrict__ Wc,
                                                  u16* __restrict__ WtQKV,
                                                  u16* __restrict__ WtO,
                                                  u16* __restrict__ WtI,
                                                  u16* __restrict__ WtF,
                                                  u16* __restrict__ WtC) {
  __shared__ float tl[32][33];
  int job = blockIdx.z;
  const float* W; u16* Wt; int K, N;
  if (job < 9) {
    int l = job / 3, p3 = job % 3;
    W = (p3 == 0 ? Wq : p3 == 1 ? Wk : Wv) + (size_t)l * 262144;
    Wt = WtQKV + (size_t)l * 786432 + (size_t)p3 * 262144;
    K = 512; N = 512;
  } else if (job < 12) {
    int l = job - 9; W = Wo + (size_t)l * 262144; Wt = WtO + (size_t)l * 262144;
    K = 512; N = 512;
  } else if (job < 15) {
    int l = job - 12; W = Wi + (size_t)l * 393216; Wt = WtI + (size_t)l * 393216;
    K = 512; N = 768;
  } else if (job < 18) {
    int l = job - 15; W = Wf + (size_t)l * 393216; Wt = WtF + (size_t)l * 393216;
    K = 768; N = 512;
  } else {
    W = Wc; Wt = WtC; K = 512; N = 100;
  }
  int n0 = blockIdx.x * 32, k0 = blockIdx.y * 32;
  if (n0 >= N || k0 >= K) return;
  int c = threadIdx.x & 31, r8 = threadIdx.x >> 5;
#pragma unroll
  for (int p = 0; p < 4; ++p) {
    int r = r8 + p * 8;
    int k = k0 + r, n = n0 + c;
    tl[r][c] = (k < K && n < N) ? W[(size_t)k * N + n] : 0.f;
  }
  __syncthreads();
#pragma unroll
  for (int p = 0; p < 4; ++p) {
    int r = r8 + p * 8;
    int n = n0 + r, k = k0 + c;
    if (n < N && k < K) Wt[(size_t)n * K + k] = f2b(tl[c][r]);
  }
}

// ---------------------------------------------------------------------------
// 128x64-tile bf16 MFMA GEMM: C[M,N] = A[M,K] @ B[N,K]^T (+bias, +gelu).
// VT=1 (QKV use): cols >= 1024 (v block) additionally written TRANSPOSED to
// vT [z=b*8+h][d][j] (fuses the old vtrans kernel into the epilogue).
// ---------------------------------------------------------------------------
template <int EPI, int VT, typename CT>
__global__ __launch_bounds__(256) void gemm128(const u16* __restrict__ A,
                                               const u16* __restrict__ B,
                                               const float* __restrict__ bias,
                                               CT* __restrict__ C,
                                               int M, int N, int K,
                                               int lda, int ldb, int ldc,
                                               u16* __restrict__ vTout) {
  __shared__ u16 As[128][72];
  __shared__ u16 Bs[64][72];
  int t = threadIdx.x;
  int m0 = blockIdx.y * 128, n0 = blockIdx.x * 64;
  int w = t >> 6, l = t & 63;
  int wr = w >> 1, wc = w & 1, lr = l & 15, kg = l >> 4;
  f32x4 acc[4][2] = {};
  for (int k0 = 0; k0 < K; k0 += 64) {
#pragma unroll
    for (int p = 0; p < 4; ++p) {
      int c = t + (p << 8);
      int row = c >> 3, q = c & 7;
      *(uint4*)(&As[row][q * 8]) =
          *(const uint4*)(A + (size_t)(m0 + row) * lda + k0 + q * 8);
    }
#pragma unroll
    for (int p = 0; p < 2; ++p) {
      int c = t + (p << 8);
      int row = c >> 3, q = c & 7;
      *(uint4*)(&Bs[row][q * 8]) =
          *(const uint4*)(B + (size_t)(n0 + row) * ldb + k0 + q * 8);
    }
    __syncthreads();
#pragma unroll
    for (int s = 0; s < 2; ++s) {
      bf16x8 a[4], bb[2];
#pragma unroll
      for (int m = 0; m < 4; ++m)
        a[m] = *(const bf16x8*)(&As[wr * 64 + m * 16 + lr][kg * 8 + s * 32]);
#pragma unroll
      for (int n = 0; n < 2; ++n)
        bb[n] = *(const bf16x8*)(&Bs[wc * 32 + n * 16 + lr][kg * 8 + s * 32]);
#pragma unroll
      for (int m = 0; m < 4; ++m)
#pragma unroll
        for (int n = 0; n < 2; ++n)
          acc[m][n] = __builtin_amdgcn_mfma_f32_16x16x32_bf16(a[m], bb[n], acc[m][n], 0, 0, 0);
    }
    __syncthreads();
  }
#pragma unroll
  for (int m = 0; m < 4; ++m)
#pragma unroll
    for (int n = 0; n < 2; ++n) {
      int col = n0 + wc * 32 + n * 16 + lr;
      float bv = (EPI >= 1) ? bias[col] : 0.f;
      int rowb = m0 + wr * 64 + m * 16 + kg * 4;
      float vv[4];
#pragma unroll
      for (int r = 0; r < 4; ++r) {
        float v = acc[m][n][r] + bv;
        if (EPI == 2) v = gelu_exact(v);
        vv[r] = v;
        if constexpr (sizeof(CT) == 2) {
          ((u16*)C)[(size_t)(rowb + r) * ldc + col] = f2b(v);
        } else {
          ((float*)C)[(size_t)(rowb + r) * ldc + col] = v;
        }
      }
      if (VT) {
        if (col >= 1024 && rowb < 4096) {
          int zz = (rowb >> 9) * 8 + ((col - 1024) >> 6);
          int dd = (col - 1024) & 63;
          ushort4 o4 = { f2b(vv[0]), f2b(vv[1]), f2b(vv[2]), f2b(vv[3]) };
          *(ushort4*)(vTout + (size_t)zz * 32768 + (size_t)dd * 512 + (rowb & 511)) = o4;
        }
      }
    }
}

// ---------------------------------------------------------------------------
// 64x64-tile bf16 MFMA GEMM (classifier only).
// ---------------------------------------------------------------------------
template <int EPI, typename CT>
__global__ __launch_bounds__(256) void gemm_bf16(const u16* __restrict__ A,
                                                 const u16* __restrict__ B,
                                                 const float* __restrict__ bias,
                                                 CT* __restrict__ C,
                                                 int M, int N, int K,
                                                 int lda, int ldb, int ldc) {
  __shared__ u16 As[64][72];
  __shared__ u16 Bs[64][72];
  int t = threadIdx.x;
  int m0 = blockIdx.y * 64, n0 = blockIdx.x * 64;
  int w = t >> 6, l = t & 63;
  int wr = w >> 1, wc = w & 1, lr = l & 15, kg = l >> 4;
  f32x4 acc[2][2] = {};
  for (int k0 = 0; k0 < K; k0 += 64) {
#pragma unroll
    for (int p = 0; p < 2; ++p) {
      int c = t + (p << 8);
      int row = c >> 3, q = c & 7;
      uint4 av = *(const uint4*)(A + (size_t)(m0 + row) * lda + k0 + q * 8);
      *(uint4*)(&As[row][q * 8]) = av;
      uint4 bv = make_uint4(0u, 0u, 0u, 0u);
      if (n0 + row < N) bv = *(const uint4*)(B + (size_t)(n0 + row) * ldb + k0 + q * 8);
      *(uint4*)(&Bs[row][q * 8]) = bv;
    }
    __syncthreads();
#pragma unroll
    for (int s = 0; s < 2; ++s) {
      bf16x8 a0 = *(const bf16x8*)(&As[wr * 32 + lr][kg * 8 + s * 32]);
      bf16x8 a1 = *(const bf16x8*)(&As[wr * 32 + 16 + lr][kg * 8 + s * 32]);
      bf16x8 b0 = *(const bf16x8*)(&Bs[wc * 32 + lr][kg * 8 + s * 32]);
      bf16x8 b1 = *(const bf16x8*)(&Bs[wc * 32 + 16 + lr][kg * 8 + s * 32]);
      acc[0][0] = __builtin_amdgcn_mfma_f32_16x16x32_bf16(a0, b0, acc[0][0], 0, 0, 0);
      acc[0][1] = __builtin_amdgcn_mfma_f32_16x16x32_bf16(a0, b1, acc[0][1], 0, 0, 0);
      acc[1][0] = __builtin_amdgcn_mfma_f32_16x16x32_bf16(a1, b0, acc[1][0], 0, 0, 0);
      acc[1][1] = __builtin_amdgcn_mfma_f32_16x16x32_bf16(a1, b1, acc[1][1], 0, 0, 0);
    }
    __syncthreads();
  }
#pragma unroll
  for (int m = 0; m < 2; ++m)
#pragma unroll
    for (int n = 0; n < 2; ++n) {
      int col = n0 + wc * 32 + n * 16 + lr;
      if (col < N) {
        float bv = (EPI >= 1) ? bias[col] : 0.f;
#pragma unroll
        for (int r = 0; r < 4; ++r) {
          int row = m0 + wr * 32 + m * 16 + kg * 4 + r;
          float v = acc[m][n][r] + bv;
          if (EPI == 2) v = gelu_exact(v);
          if constexpr (sizeof(CT) == 2) {
            ((u16*)C)[(size_t)row * ldc + col] = f2b(v);
          } else {
            ((float*)C)[(size_t)row * ldc + col] = v;
          }
        }
      }
    }
}

// ---------------------------------------------------------------------------
// Fused disentangled attention, 8-way split-j, bias on-the-fly via MFMA.
// Adaptive window: F = ceil(width/16) frags; off-diagonal tiles have narrow
// bucket windows (log compression) -> ~30% less bias MFMA + staging.
// K fragments direct from global (L2-resident after XCD chunking); P buffer
// aliases U1 behind a barrier -> LDS 38.9 KB -> 4 blocks/CU.
// Softmax in exp2 domain; po written packed (32B/lane contiguous).
// ---------------------------------------------------------------------------
__global__ __launch_bounds__(256) void attn_fused(const u16* __restrict__ qkv,
                                                  const u16* __restrict__ vT,
                                                  const float* __restrict__ mask,
                                                  const int* __restrict__ crel,
                                                  u16* __restrict__ po,
                                                  float* __restrict__ pms) {
  __shared__ u16 U1[128][72];     // pk window -> b1 view [64][136] -> P [4][16][72]
  __shared__ u16 U2[128][72];     // pq window -> b2 [128][72]
  __shared__ u16 crl16[1024];     // -> 38912 B total
  int t = threadIdx.x;
  int wg = blockIdx.x;            // 0..4095
  int xcd = wg & 7, qq = wg >> 3;
  int z = xcd * 8 + (qq >> 6);    // b*8+h, chunked per XCD
  int rem = qq & 63;
  int it = rem >> 3, js = rem & 7;
  int b = z >> 3, h = z & 7;
  int i0 = it * 64, j0 = js * 64;
  int w = t >> 6, l = t & 63;
  int lr = l & 15, kg = l >> 4;

  int ib = bucket_clip(i0 - j0 - 63);      // min bucket (crel monotone)
  int ie = bucket_clip(i0 - j0 + 63);      // max bucket
  int F = (ie - ib + 16) >> 4;             // frag count 1..8

  for (int c = t; c < 1023; c += 256) crl16[c] = (u16)crel[c];
  // stage pk/pq windows: only F*16 rows
  for (int c = t; c < F * 128; c += 256) {
    int row = c >> 3, off = (c & 7) * 8;
    int rw = ib + row;
    rw = rw > 511 ? 511 : rw;
    const u16* relrow = qkv + (size_t)(4096 + rw) * 1536 + h * 64;
    *(uint4*)(&U1[row][off]) = *(const uint4*)(relrow + 512 + off);  // pk
    *(uint4*)(&U2[row][off]) = *(const uint4*)(relrow + off);        // pq
  }
  // q and K fragments direct from global (L2-resident)
  const u16* qrow = qkv + (size_t)(b * 512 + i0 + w * 16 + lr) * 1536 + h * 64;
  bf16x8 qa0 = *(const bf16x8*)(qrow + kg * 8);
  bf16x8 qa1 = *(const bf16x8*)(qrow + kg * 8 + 32);
  bf16x8 kb[4][2];
#pragma unroll
  for (int nf = 0; nf < 4; ++nf) {
    const u16* krow = qkv + (size_t)(b * 512 + j0 + nf * 16 + lr) * 1536 + 512 + h * 64;
    kb[nf][0] = *(const bf16x8*)(krow + kg * 8);
    kb[nf][1] = *(const bf16x8*)(krow + kg * 8 + 32);
  }
  __syncthreads();  // windows staged

  // QK^T scores
  f32x4 sc[4];
#pragma unroll
  for (int nf = 0; nf < 4; ++nf) {
    f32x4 a = {};
    a = __builtin_amdgcn_mfma_f32_16x16x32_bf16(qa0, kb[nf][0], a, 0, 0, 0);
    a = __builtin_amdgcn_mfma_f32_16x16x32_bf16(qa1, kb[nf][1], a, 0, 0, 0);
    sc[nf] = a;
  }
  // bias1 = Q @ pk_win^T (only F frags)
  f32x4 b1a[8] = {};
#pragma unroll
  for (int f = 0; f < 8; ++f) {
    if (f < F) {
      bf16x8 p0 = *(const bf16x8*)(&U1[f * 16 + lr][kg * 8]);
      bf16x8 p1 = *(const bf16x8*)(&U1[f * 16 + lr][kg * 8 + 32]);
      f32x4 a = {};
      a = __builtin_amdgcn_mfma_f32_16x16x32_bf16(qa0, p0, a, 0, 0, 0);
      a = __builtin_amdgcn_mfma_f32_16x16x32_bf16(qa1, p1, a, 0, 0, 0);
      b1a[f] = a;
    }
  }
  // bias2 = pq_win @ K^T : wave w owns row-frags {w, w+4} (if < F)
  f32x4 b2a[2][4] = {};
#pragma unroll
  for (int g = 0; g < 2; ++g) {
    int fr = w + g * 4;
    if (fr < F) {
      bf16x8 a0 = *(const bf16x8*)(&U2[fr * 16 + lr][kg * 8]);
      bf16x8 a1 = *(const bf16x8*)(&U2[fr * 16 + lr][kg * 8 + 32]);
#pragma unroll
      for (int nf = 0; nf < 4; ++nf) {
        f32x4 a = {};
        a = __builtin_amdgcn_mfma_f32_16x16x32_bf16(a0, kb[nf][0], a, 0, 0, 0);
        a = __builtin_amdgcn_mfma_f32_16x16x32_bf16(a1, kb[nf][1], a, 0, 0, 0);
        b2a[g][nf] = a;
      }
    }
  }
  __syncthreads();  // all window reads done -> overwrite with bias tiles
  u16* b1 = &U1[0][0];  // b1 view [64][136]
#pragma unroll
  for (int f = 0; f < 8; ++f) {
    if (f < F) {
#pragma unroll
      for (int r = 0; r < 4; ++r)
        b1[(w * 16 + kg * 4 + r) * 136 + f * 16 + lr] = f2b(b1a[f][r]);
    }
  }
#pragma unroll
  for (int g = 0; g < 2; ++g) {
    int fr = w + g * 4;
    if (fr < F) {
#pragma unroll
      for (int nf = 0; nf < 4; ++nf)
#pragma unroll
        for (int r = 0; r < 4; ++r)
          U2[fr * 16 + kg * 4 + r][nf * 16 + lr] = f2b(b2a[g][nf][r]);
    }
  }
  __syncthreads();  // bias tiles ready (b2 read cross-wave)

  // V fragments direct from global (issued early, consumed after softmax)
  bf16x8 vb[4][2];
#pragma unroll
  for (int nf = 0; nf < 4; ++nf) {
    const u16* vrow = vT + (size_t)z * 32768 + (size_t)(nf * 16 + lr) * 512 + j0;
    vb[nf][0] = *(const bf16x8*)(vrow + kg * 8);
    vb[nf][1] = *(const bf16x8*)(vrow + kg * 8 + 32);
  }

  // gather bias (LDS) + mask + softmax in exp2 domain (single tile)
  const float SC2 = INV_SCALE * 1.4426950408889634f;
  float mi[4], mj[4];
#pragma unroll
  for (int r = 0; r < 4; ++r) mi[r] = mask[b * 512 + i0 + w * 16 + kg * 4 + r];
#pragma unroll
  for (int nf = 0; nf < 4; ++nf) mj[nf] = mask[b * 512 + j0 + nf * 16 + lr];
  float lgv[4][4];
  bool ok[4][4];
  float tmax[4] = {NEGMAX, NEGMAX, NEGMAX, NEGMAX};
  int iloc = w * 16 + kg * 4;
#pragma unroll
  for (int nf = 0; nf < 4; ++nf) {
    int jloc = nf * 16 + lr;
    int relc = i0 + iloc - (j0 + jloc) + 511;
#pragma unroll
    for (int r = 0; r < 4; ++r) {
      int idx = crl16[relc + r] - ib;
      float bias = b2f(b1[(iloc + r) * 136 + idx]) + b2f(U2[idx][jloc]);
      bool o_ = (mi[r] * mj[nf]) > 0.f;
      float v = o_ ? (sc[nf][r] + bias) * SC2 : NEGMAX;
      ok[nf][r] = o_;
      lgv[nf][r] = v;
      tmax[r] = fmaxf(tmax[r], v);
    }
  }
#pragma unroll
  for (int r = 0; r < 4; ++r) {
#pragma unroll
    for (int off = 8; off; off >>= 1) tmax[r] = fmaxf(tmax[r], __shfl_xor(tmax[r], off));
  }
  float tsum[4];
#pragma unroll
  for (int r = 0; r < 4; ++r) {
    float mn = tmax[r];
    float ls = 0.f;
#pragma unroll
    for (int nf = 0; nf < 4; ++nf) {
      float p = ok[nf][r] ? exp2f(lgv[nf][r] - mn) : 0.f;
      lgv[nf][r] = p;
      ls += p;
    }
    tsum[r] = ls;
  }
#pragma unroll
  for (int r = 0; r < 4; ++r) {
#pragma unroll
    for (int off = 8; off; off >>= 1) tsum[r] += __shfl_xor(tsum[r], off);
  }
  __syncthreads();  // all gathers done -> alias P buffer onto U1
  u16 (*ps)[16][72] = (u16(*)[16][72]) & U1[0][0];
#pragma unroll
  for (int nf = 0; nf < 4; ++nf)
#pragma unroll
    for (int r = 0; r < 4; ++r) ps[w][kg * 4 + r][nf * 16 + lr] = f2b(lgv[nf][r]);
  bf16x8 pa0 = *(const bf16x8*)(&ps[w][lr][kg * 8]);
  bf16x8 pa1 = *(const bf16x8*)(&ps[w][lr][kg * 8 + 32]);
  // PV
  f32x4 o[4] = {};
#pragma unroll
  for (int nf = 0; nf < 4; ++nf) {
    o[nf] = __builtin_amdgcn_mfma_f32_16x16x32_bf16(pa0, vb[nf][0], o[nf], 0, 0, 0);
    o[nf] = __builtin_amdgcn_mfma_f32_16x16x32_bf16(pa1, vb[nf][1], o[nf], 0, 0, 0);
  }
  // packed partial write: 32B contiguous per lane
  unsigned int pk[8];
#pragma unroll
  for (int nf = 0; nf < 4; ++nf) {
    pk[nf * 2 + 0] = (unsigned int)f2b(o[nf][0]) | ((unsigned int)f2b(o[nf][1]) << 16);
    pk[nf * 2 + 1] = (unsigned int)f2b(o[nf][2]) | ((unsigned int)f2b(o[nf][3]) << 16);
  }
  size_t base = (((((size_t)js * 64 + z) * 8 + it) * 4 + w) * 64 + l) * 16;
  *(uint4*)(po + base) = make_uint4(pk[0], pk[1], pk[2], pk[3]);
  *(uint4*)(po + base + 8) = make_uint4(pk[4], pk[5], pk[6], pk[7]);
#pragma unroll
  for (int r = 0; r < 4; ++r) {
    if (lr == 0) {
      int i = i0 + w * 16 + kg * 4 + r;
      size_t mb = (((size_t)js * 64 + z) * 512 + i) * 2;
      pms[mb + 0] = tmax[r];   // log2 domain
      pms[mb + 1] = tsum[r];
    }
  }
}

// ---------------------------------------------------------------------------
// Merge 8 j-split partials (packed layout) -> normalized ctx (bf16).
// ---------------------------------------------------------------------------
__global__ __launch_bounds__(256) void merge_kernel(const u16* __restrict__ po,
                                                    const float* __restrict__ pms,
                                                    u16* __restrict__ ctx) {
  int t = threadIdx.x;
  int w_ = t >> 6, d = t & 63;
  int row = blockIdx.x * 4 + w_;  // 0..32767
  int z = row >> 9, i = row & 511;
  int b = z >> 3, h = z & 7;
  int it = i >> 6, ii = i & 63;
  int aw = ii >> 4, akg = (ii >> 2) & 3, ar = ii & 3;
  int alr = d & 15, anf = d >> 4;
  float mv[8], sv[8], m = NEGMAX;
#pragma unroll
  for (int js = 0; js < 8; ++js) {
    size_t mb = (((size_t)js * 64 + z) * 512 + i) * 2;
    mv[js] = pms[mb + 0];
    sv[js] = pms[mb + 1];
    m = fmaxf(m, mv[js]);
  }
  float o = 0.f, s = 0.f;
#pragma unroll
  for (int js = 0; js < 8; ++js) {
    float wgt = (mv[js] <= -1e37f) ? 0.f : exp2f(mv[js] - m);
    size_t pb = (((((size_t)js * 64 + z) * 8 + it) * 4 + aw) * 64 + (akg * 16 + alr)) * 16
                + anf * 4 + ar;
    o += wgt * b2f(po[pb]);
    s += wgt * sv[js];
  }
  float r = (s > 0.f) ? o / s : 0.f;
  ctx[(size_t)(b * 512 + i) * 512 + h * 64 + d] = f2b(r);
}

// ---------------------------------------------------------------------------
// Host launch
// ---------------------------------------------------------------------------
extern "C" void kernel_launch(void* const* d_in, const int* in_sizes, int n_in,
                              void* d_out, int out_size, void* d_ws, size_t ws_size,
                              hipStream_t stream) {
  const float* x       = (const float*)d_in[0];
  const float* mask    = (const float*)d_in[1];
  const float* emb_s   = (const float*)d_in[2];
  const float* emb_b   = (const float*)d_in[3];
  const float* rel_emb = (const float*)d_in[4];
  const float* rel_s   = (const float*)d_in[5];
  const float* rel_b   = (const float*)d_in[6];
  const float* Wq = (const float*)d_in[7];
  const float* bq = (const float*)d_in[8];
  const float* Wk = (const float*)d_in[9];
  const float* bk = (const float*)d_in[10];
  const float* Wv = (const float*)d_in[11];
  const float* bv = (const float*)d_in[12];
  const float* Wo = (const float*)d_in[13];
  const float* bo = (const float*)d_in[14];
  const float* as_ = (const float*)d_in[15];
  const float* ab_ = (const float*)d_in[16];
  const float* Wi = (const float*)d_in[17];
  const float* bi = (const float*)d_in[18];
  const float* Wf = (const float*)d_in[19];
  const float* bf_ = (const float*)d_in[20];
  const float* fs_ = (const float*)d_in[21];
  const float* fb_ = (const float*)d_in[22];
  const float* Wc = (const float*)d_in[23];
  const float* bc = (const float*)d_in[24];
  float* out = (float*)d_out;

  char* p = (char*)d_ws;
  auto alloc = [&](size_t bytes) {
    char* r = p;
    p += (bytes + 255) & ~(size_t)255;
    return r;
  };
  float* hcat = (float*)alloc((size_t)4608 * 512 * 4);
  float* tmpA = (float*)alloc((size_t)4096 * 512 * 4);
  u16* mid  = (u16*)alloc((size_t)4096 * 768 * 2);
  u16* hbf  = (u16*)alloc((size_t)4608 * 512 * 2);
  u16* qkv  = (u16*)alloc((size_t)4608 * 1536 * 2);     // q|k|v (+pq|pk rows)
  u16* vT   = (u16*)alloc((size_t)64 * 64 * 512 * 2);   // [bh][d][j]
  u16* ctxb = (u16*)alloc((size_t)4096 * 512 * 2);
  u16* po   = (u16*)alloc((size_t)8 * 64 * 512 * 64 * 2);   // packed partials
  float* pms = (float*)alloc((size_t)8 * 64 * 512 * 2 * 4); // [js][bh][i][2]
  u16* WtQKV = (u16*)alloc((size_t)3 * 1536 * 512 * 2);
  u16* WtO  = (u16*)alloc((size_t)3 * 512 * 512 * 2);
  u16* WtI  = (u16*)alloc((size_t)3 * 768 * 512 * 2);
  u16* WtF  = (u16*)alloc((size_t)3 * 512 * 768 * 2);
  u16* WtC  = (u16*)alloc((size_t)100 * 512 * 2);
  float* bqkv = (float*)alloc((size_t)3 * 1536 * 4);
  int* crel = (int*)alloc((size_t)1024 * 4);

  tables_kernel<<<22, 256, 0, stream>>>(bq, bk, bv, crel, bqkv);
  wtrans_all<<<dim3(24, 24, 19), 256, 0, stream>>>(Wq, Wk, Wv, Wo, Wi, Wf, Wc,
                                                   WtQKV, WtO, WtI, WtF, WtC);
  ln_kernel<false, true><<<1024, 256, 0, stream>>>(x, nullptr, emb_s, emb_b, mask,
                                                   hcat, hbf, 4096);
  ln_kernel<false, false><<<128, 256, 0, stream>>>(rel_emb, nullptr, rel_s, rel_b, nullptr,
                                                   hcat + (size_t)4096 * 512,
                                                   hbf + (size_t)4096 * 512, 512);

  for (int l = 0; l < 3; ++l) {
    // fused q|k|v (+pq|pk) projection, vT written in epilogue
    gemm128<1, 1, u16><<<dim3(24, 36), 256, 0, stream>>>(
        hbf, WtQKV + (size_t)l * 786432, bqkv + l * 1536, qkv,
        4608, 1536, 512, 512, 512, 1536, vT);
    // fused QK^T + on-the-fly MFMA bias + XSoftmax + PV, 8-way split-j
    attn_fused<<<4096, 256, 0, stream>>>(qkv, vT, mask, crel, po, pms);
    merge_kernel<<<8192, 256, 0, stream>>>(po, pms, ctxb);
    // O proj -> fp32, LN(+h)
    gemm128<1, 0, float><<<dim3(8, 32), 256, 0, stream>>>(
        ctxb, WtO + (size_t)l * 262144, bo + l * 512, tmpA, 4096, 512, 512,
        512, 512, 512, nullptr);
    ln_kernel<true, false><<<1024, 256, 0, stream>>>(tmpA, hcat, as_ + l * 512, ab_ + l * 512,
                                                     nullptr, hcat, hbf, 4096);
    // FFN
    gemm128<2, 0, u16><<<dim3(12, 32), 256, 0, stream>>>(
        hbf, WtI + (size_t)l * 393216, bi + l * 768, mid, 4096, 768, 512,
        512, 512, 768, nullptr);
    gemm128<1, 0, float><<<dim3(8, 32), 256, 0, stream>>>(
        mid, WtF + (size_t)l * 393216, bf_ + l * 512, tmpA, 4096, 512, 768,
        768, 768, 512, nullptr);
    ln_kernel<true, false><<<1024, 256, 0, stream>>>(tmpA, hcat, fs_ + l * 512, fb_ + l * 512,
                                                     nullptr, hcat, hbf, 4096);
  }
  gemm_bf16<1, float><<<dim3(2, 64), 256, 0, stream>>>(
      hbf, WtC, bc, out, 4096, 100, 512, 512, 512, 100);
}

// Round 12
// 770.077 us; speedup vs baseline: 1.0292x; 1.0292x over previous
//
#include <hip/hip_runtime.h>
#include <hip/hip_bf16.h>
#include <math.h>

// B=8, S=512, HID=512, HEADS=8, DH=64, FF=768, NL=3, SPAN=256, MAXP=512, VOCAB=100
#define EPS_LN 1e-7f
#define INV_SCALE 0.072168783648703221f   // 1/sqrt(64*3)
#define NEGMAX -3.402823466e38f

typedef unsigned short u16;
typedef __attribute__((ext_vector_type(8))) short bf16x8;  // 8 bf16 = 4 VGPRs
typedef __attribute__((ext_vector_type(4))) float f32x4;

__device__ __forceinline__ u16 f2b(float f) {
  union { float f; unsigned int u; } v; v.f = f;
  unsigned int r = v.u + 0x7FFFu + ((v.u >> 16) & 1u);
  return (u16)(r >> 16);
}
__device__ __forceinline__ float b2f(u16 u) {
  union { unsigned int u; float f; } v; v.u = ((unsigned int)u) << 16;
  return v.f;
}
__device__ __forceinline__ float gelu_exact(float v) {
  return 0.5f * v * (1.f + erff(v * 0.70710678118654752440f));
}
// DeBERTa log-bucket for a single rel value (bit-exact with table build)
__device__ __forceinline__ int bucket_clip(int rel) {
  int a = (rel < 128 && rel > -128) ? 127 : (rel < 0 ? -rel : rel);
  int bucket;
  if (a <= 128) {
    bucket = rel;
  } else {
    double lp = ceil(log((double)a / 128.0) / log(511.0 / 128.0) * 127.0) + 128.0;
    int l = (int)lp;
    bucket = (rel > 0) ? l : -l;
  }
  int c = bucket + 256;
  return c < 0 ? 0 : (c > 511 ? 511 : c);
}

// ---------------------------------------------------------------------------
// Small tables: crel (1023) + concat bias [3][1536] = bq|bk|bv.
// ---------------------------------------------------------------------------
__global__ __launch_bounds__(256) void tables_kernel(const float* __restrict__ bq,
                                                     const float* __restrict__ bk,
                                                     const float* __restrict__ bv,
                                                     int* __restrict__ crel,
                                                     float* __restrict__ bqkv) {
  int i = blockIdx.x * 256 + threadIdx.x;
  if (i < 1023) crel[i] = bucket_clip(i - 511);
  int j = i - 1024;
  if (j >= 0 && j < 4608) {
    int l = j / 1536, c = j - l * 1536;
    float v = (c < 512) ? bq[l * 512 + c]
                        : (c < 1024) ? bk[l * 512 + c - 512] : bv[l * 512 + c - 1024];
    bqkv[j] = v;
  }
}

// ---------------------------------------------------------------------------
// LayerNorm over 512 cols; writes fp32 master and optional bf16 mirror.
// ---------------------------------------------------------------------------
template <bool RESID, bool MASK>
__global__ __launch_bounds__(256) void ln_kernel(const float* __restrict__ x,
                                                 const float* __restrict__ res,
                                                 const float* __restrict__ gam,
                                                 const float* __restrict__ bet,
                                                 const float* __restrict__ mask,
                                                 float* __restrict__ out,
                                                 u16* __restrict__ outb, int nrows) {
  int w = threadIdx.x >> 6, ln = threadIdx.x & 63;
  int row = blockIdx.x * 4 + w;
  if (row >= nrows) return;
  const float* xr = x + (size_t)row * 512;
  float v[8];
#pragma unroll
  for (int c = 0; c < 2; ++c) {
    float4 a = *(const float4*)(xr + (ln << 3) + (c << 2));
    v[c * 4 + 0] = a.x; v[c * 4 + 1] = a.y; v[c * 4 + 2] = a.z; v[c * 4 + 3] = a.w;
    if (RESID) {
      float4 r4 = *(const float4*)(res + (size_t)row * 512 + (ln << 3) + (c << 2));
      v[c * 4 + 0] += r4.x; v[c * 4 + 1] += r4.y; v[c * 4 + 2] += r4.z; v[c * 4 + 3] += r4.w;
    }
  }
  float sum = 0.f;
#pragma unroll
  for (int c = 0; c < 8; ++c) sum += v[c];
#pragma unroll
  for (int off = 32; off; off >>= 1) sum += __shfl_xor(sum, off);
  float mu = sum * (1.f / 512.f);
  float vs = 0.f;
#pragma unroll
  for (int c = 0; c < 8; ++c) { float d = v[c] - mu; vs += d * d; }
#pragma unroll
  for (int off = 32; off; off >>= 1) vs += __shfl_xor(vs, off);
  float rstd = 1.f / sqrtf(vs * (1.f / 512.f) + EPS_LN);
  float mk = MASK ? mask[row] : 1.f;
  float* orow = out + (size_t)row * 512;
  u16* brow = outb ? outb + (size_t)row * 512 : nullptr;
#pragma unroll
  for (int c = 0; c < 2; ++c) {
    int col = (ln << 3) + (c << 2);
    float o[4];
#pragma unroll
    for (int q = 0; q < 4; ++q)
      o[q] = ((v[c * 4 + q] - mu) * rstd * gam[col + q] + bet[col + q]) * mk;
    *(float4*)(orow + col) = make_float4(o[0], o[1], o[2], o[3]);
    if (brow) {
      ushort4 ob = { f2b(o[0]), f2b(o[1]), f2b(o[2]), f2b(o[3]) };
      *(ushort4*)(brow + col) = ob;
    }
  }
}

// ---------------------------------------------------------------------------
// ALL weight transposes (f32 [K][N] -> bf16 [N][K]) in ONE dispatch.
// job = blockIdx.z: 0-8 QKV(l,part), 9-11 O, 12-14 I, 15-17 F, 18 C.
// ---------------------------------------------------------------------------
__global__ __launch_bounds__(256) void wtrans_all(const float* __restrict__ Wq,
                                                  const float* __restrict__ Wk,
                                                  const float* __restrict__ Wv,
                                                  const float* __restrict__ Wo,
                                                  const float* __restrict__ Wi,
                                                  const float* __restrict__ Wf,
                                                  const float* __restrict__ Wc,
                                                  u16* __restrict__ WtQKV,
                                                  u16* __restrict__ WtO,
                                                  u16* __restrict__ WtI,
                                                  u16* __restrict__ WtF,
                                                  u16* __restrict__ WtC) {
  __shared__ float tl[32][33];
  int job = blockIdx.z;
  const float* W; u16* Wt; int K, N;
  if (job < 9) {
    int l = job / 3, p3 = job % 3;
    W = (p3 == 0 ? Wq : p3 == 1 ? Wk : Wv) + (size_t)l * 262144;
    Wt = WtQKV + (size_t)l * 786432 + (size_t)p3 * 262144;
    K = 512; N = 512;
  } else if (job < 12) {
    int l = job - 9; W = Wo + (size_t)l * 262144; Wt = WtO + (size_t)l * 262144;
    K = 512; N = 512;
  } else if (job < 15) {
    int l = job - 12; W = Wi + (size_t)l * 393216; Wt = WtI + (size_t)l * 393216;
    K = 512; N = 768;
  } else if (job < 18) {
    int l = job - 15; W = Wf + (size_t)l * 393216; Wt = WtF + (size_t)l * 393216;
    K = 768; N = 512;
  } else {
    W = Wc; Wt = WtC; K = 512; N = 100;
  }
  int n0 = blockIdx.x * 32, k0 = blockIdx.y * 32;
  if (n0 >= N || k0 >= K) return;
  int c = threadIdx.x & 31, r8 = threadIdx.x >> 5;
#pragma unroll
  for (int p = 0; p < 4; ++p) {
    int r = r8 + p * 8;
    int k = k0 + r, n = n0 + c;
    tl[r][c] = (k < K && n < N) ? W[(size_t)k * N + n] : 0.f;
  }
  __syncthreads();
#pragma unroll
  for (int p = 0; p < 4; ++p) {
    int r = r8 + p * 8;
    int n = n0 + r, k = k0 + c;
    if (n < N && k < K) Wt[(size_t)n * K + k] = f2b(tl[c][r]);
  }
}

// ---------------------------------------------------------------------------
// 128x64-tile bf16 MFMA GEMM: C[M,N] = A[M,K] @ B[N,K]^T (+bias, +gelu).
// VT=1 (QKV use): cols >= 1024 (v block) additionally written TRANSPOSED to
// vT [z=b*8+h][d][j] (vtrans fused into epilogue).
// ---------------------------------------------------------------------------
template <int EPI, int VT, typename CT>
__global__ __launch_bounds__(256) void gemm128(const u16* __restrict__ A,
                                               const u16* __restrict__ B,
                                               const float* __restrict__ bias,
                                               CT* __restrict__ C,
                                               int M, int N, int K,
                                               int lda, int ldb, int ldc,
                                               u16* __restrict__ vTout) {
  __shared__ u16 As[128][72];
  __shared__ u16 Bs[64][72];
  int t = threadIdx.x;
  int m0 = blockIdx.y * 128, n0 = blockIdx.x * 64;
  int w = t >> 6, l = t & 63;
  int wr = w >> 1, wc = w & 1, lr = l & 15, kg = l >> 4;
  f32x4 acc[4][2] = {};
  for (int k0 = 0; k0 < K; k0 += 64) {
#pragma unroll
    for (int p = 0; p < 4; ++p) {
      int c = t + (p << 8);
      int row = c >> 3, q = c & 7;
      *(uint4*)(&As[row][q * 8]) =
          *(const uint4*)(A + (size_t)(m0 + row) * lda + k0 + q * 8);
    }
#pragma unroll
    for (int p = 0; p < 2; ++p) {
      int c = t + (p << 8);
      int row = c >> 3, q = c & 7;
      *(uint4*)(&Bs[row][q * 8]) =
          *(const uint4*)(B + (size_t)(n0 + row) * ldb + k0 + q * 8);
    }
    __syncthreads();
#pragma unroll
    for (int s = 0; s < 2; ++s) {
      bf16x8 a[4], bb[2];
#pragma unroll
      for (int m = 0; m < 4; ++m)
        a[m] = *(const bf16x8*)(&As[wr * 64 + m * 16 + lr][kg * 8 + s * 32]);
#pragma unroll
      for (int n = 0; n < 2; ++n)
        bb[n] = *(const bf16x8*)(&Bs[wc * 32 + n * 16 + lr][kg * 8 + s * 32]);
#pragma unroll
      for (int m = 0; m < 4; ++m)
#pragma unroll
        for (int n = 0; n < 2; ++n)
          acc[m][n] = __builtin_amdgcn_mfma_f32_16x16x32_bf16(a[m], bb[n], acc[m][n], 0, 0, 0);
    }
    __syncthreads();
  }
#pragma unroll
  for (int m = 0; m < 4; ++m)
#pragma unroll
    for (int n = 0; n < 2; ++n) {
      int col = n0 + wc * 32 + n * 16 + lr;
      float bv = (EPI >= 1) ? bias[col] : 0.f;
      int rowb = m0 + wr * 64 + m * 16 + kg * 4;
      float vv[4];
#pragma unroll
      for (int r = 0; r < 4; ++r) {
        float v = acc[m][n][r] + bv;
        if (EPI == 2) v = gelu_exact(v);
        vv[r] = v;
        if constexpr (sizeof(CT) == 2) {
          ((u16*)C)[(size_t)(rowb + r) * ldc + col] = f2b(v);
        } else {
          ((float*)C)[(size_t)(rowb + r) * ldc + col] = v;
        }
      }
      if (VT) {
        if (col >= 1024 && rowb < 4096) {
          int zz = (rowb >> 9) * 8 + ((col - 1024) >> 6);
          int dd = (col - 1024) & 63;
          ushort4 o4 = { f2b(vv[0]), f2b(vv[1]), f2b(vv[2]), f2b(vv[3]) };
          *(ushort4*)(vTout + (size_t)zz * 32768 + (size_t)dd * 512 + (rowb & 511)) = o4;
        }
      }
    }
}

// ---------------------------------------------------------------------------
// 64x64-tile bf16 MFMA GEMM (classifier only).
// ---------------------------------------------------------------------------
template <int EPI, typename CT>
__global__ __launch_bounds__(256) void gemm_bf16(const u16* __restrict__ A,
                                                 const u16* __restrict__ B,
                                                 const float* __restrict__ bias,
                                                 CT* __restrict__ C,
                                                 int M, int N, int K,
                                                 int lda, int ldb, int ldc) {
  __shared__ u16 As[64][72];
  __shared__ u16 Bs[64][72];
  int t = threadIdx.x;
  int m0 = blockIdx.y * 64, n0 = blockIdx.x * 64;
  int w = t >> 6, l = t & 63;
  int wr = w >> 1, wc = w & 1, lr = l & 15, kg = l >> 4;
  f32x4 acc[2][2] = {};
  for (int k0 = 0; k0 < K; k0 += 64) {
#pragma unroll
    for (int p = 0; p < 2; ++p) {
      int c = t + (p << 8);
      int row = c >> 3, q = c & 7;
      uint4 av = *(const uint4*)(A + (size_t)(m0 + row) * lda + k0 + q * 8);
      *(uint4*)(&As[row][q * 8]) = av;
      uint4 bv = make_uint4(0u, 0u, 0u, 0u);
      if (n0 + row < N) bv = *(const uint4*)(B + (size_t)(n0 + row) * ldb + k0 + q * 8);
      *(uint4*)(&Bs[row][q * 8]) = bv;
    }
    __syncthreads();
#pragma unroll
    for (int s = 0; s < 2; ++s) {
      bf16x8 a0 = *(const bf16x8*)(&As[wr * 32 + lr][kg * 8 + s * 32]);
      bf16x8 a1 = *(const bf16x8*)(&As[wr * 32 + 16 + lr][kg * 8 + s * 32]);
      bf16x8 b0 = *(const bf16x8*)(&Bs[wc * 32 + lr][kg * 8 + s * 32]);
      bf16x8 b1 = *(const bf16x8*)(&Bs[wc * 32 + 16 + lr][kg * 8 + s * 32]);
      acc[0][0] = __builtin_amdgcn_mfma_f32_16x16x32_bf16(a0, b0, acc[0][0], 0, 0, 0);
      acc[0][1] = __builtin_amdgcn_mfma_f32_16x16x32_bf16(a0, b1, acc[0][1], 0, 0, 0);
      acc[1][0] = __builtin_amdgcn_mfma_f32_16x16x32_bf16(a1, b0, acc[1][0], 0, 0, 0);
      acc[1][1] = __builtin_amdgcn_mfma_f32_16x16x32_bf16(a1, b1, acc[1][1], 0, 0, 0);
    }
    __syncthreads();
  }
#pragma unroll
  for (int m = 0; m < 2; ++m)
#pragma unroll
    for (int n = 0; n < 2; ++n) {
      int col = n0 + wc * 32 + n * 16 + lr;
      if (col < N) {
        float bv = (EPI >= 1) ? bias[col] : 0.f;
#pragma unroll
        for (int r = 0; r < 4; ++r) {
          int row = m0 + wr * 32 + m * 16 + kg * 4 + r;
          float v = acc[m][n][r] + bv;
          if (EPI == 2) v = gelu_exact(v);
          if constexpr (sizeof(CT) == 2) {
            ((u16*)C)[(size_t)row * ldc + col] = f2b(v);
          } else {
            ((float*)C)[(size_t)row * ldc + col] = v;
          }
        }
      }
    }
}

// ---------------------------------------------------------------------------
// Fused disentangled attention, 8-way split-j, bias on-the-fly via MFMA.
// ROUND-10 register budget (K staged in LDS, 84 VGPR) + adaptive window
// (F = ceil(width/16) frags, wave-uniform; off-diagonal tiles compress) +
// exp2 softmax + packed po writes. LDS 50 KB -> 3 blocks/CU.
// XCD-chunked 1-D grid (wg&7 = xcd) keeps per-XCD working set L2-resident.
// ---------------------------------------------------------------------------
__global__ __launch_bounds__(256) void attn_fused(const u16* __restrict__ qkv,
                                                  const u16* __restrict__ vT,
                                                  const float* __restrict__ mask,
                                                  const int* __restrict__ crel,
                                                  u16* __restrict__ po,
                                                  float* __restrict__ pms) {
  __shared__ u16 ks[64][72];      //  9216 B (K tile; later per-wave P buffer)
  __shared__ u16 U1[128][72];     // 18432 B (pk window -> b1 view [64][136])
  __shared__ u16 U2[128][72];     // 18432 B (pq window -> b2 [128][72])
  __shared__ u16 crl16[1024];     //  2048 B   -> 50128 B total
  int t = threadIdx.x;
  int wg = blockIdx.x;            // 0..4095
  int xcd = wg & 7, qq = wg >> 3;
  int z = xcd * 8 + (qq >> 6);    // b*8+h, chunked per XCD
  int rem = qq & 63;
  int it = rem >> 3, js = rem & 7;
  int b = z >> 3, h = z & 7;
  int i0 = it * 64, j0 = js * 64;
  int w = t >> 6, l = t & 63;
  int lr = l & 15, kg = l >> 4;

  int ib = bucket_clip(i0 - j0 - 63);      // min bucket (crel monotone)
  int ie = bucket_clip(i0 - j0 + 63);      // max bucket
  int F = (ie - ib + 16) >> 4;             // frag count 1..8 (wave-uniform)

  for (int c = t; c < 1023; c += 256) crl16[c] = (u16)crel[c];
  // stage K tile
  for (int c = t; c < 512; c += 256) {
    int row = c >> 3, off = (c & 7) * 8;
    *(uint4*)(&ks[row][off]) =
        *(const uint4*)(qkv + (size_t)(b * 512 + j0 + row) * 1536 + 512 + h * 64 + off);
  }
  // stage pk/pq windows: only F*16 rows
  for (int c = t; c < F * 128; c += 256) {
    int row = c >> 3, off = (c & 7) * 8;
    int rw = ib + row;
    rw = rw > 511 ? 511 : rw;
    const u16* relrow = qkv + (size_t)(4096 + rw) * 1536 + h * 64;
    *(uint4*)(&U1[row][off]) = *(const uint4*)(relrow + 512 + off);  // pk
    *(uint4*)(&U2[row][off]) = *(const uint4*)(relrow + off);        // pq
  }

  // q fragments straight from global
  const u16* qrow = qkv + (size_t)(b * 512 + i0 + w * 16 + lr) * 1536 + h * 64;
  bf16x8 qa0 = *(const bf16x8*)(qrow + kg * 8);
  bf16x8 qa1 = *(const bf16x8*)(qrow + kg * 8 + 32);
  __syncthreads();

  // QK^T scores (4 col-frags) from LDS K
  f32x4 sc[4];
#pragma unroll
  for (int nf = 0; nf < 4; ++nf) {
    bf16x8 kb0 = *(const bf16x8*)(&ks[nf * 16 + lr][kg * 8]);
    bf16x8 kb1 = *(const bf16x8*)(&ks[nf * 16 + lr][kg * 8 + 32]);
    f32x4 a = {};
    a = __builtin_amdgcn_mfma_f32_16x16x32_bf16(qa0, kb0, a, 0, 0, 0);
    a = __builtin_amdgcn_mfma_f32_16x16x32_bf16(qa1, kb1, a, 0, 0, 0);
    sc[nf] = a;
  }
  // bias1 = Q @ pk_win^T (only F frags)
  f32x4 b1a[8] = {};
#pragma unroll
  for (int f = 0; f < 8; ++f) {
    if (f < F) {
      bf16x8 p0 = *(const bf16x8*)(&U1[f * 16 + lr][kg * 8]);
      bf16x8 p1 = *(const bf16x8*)(&U1[f * 16 + lr][kg * 8 + 32]);
      f32x4 a = {};
      a = __builtin_amdgcn_mfma_f32_16x16x32_bf16(qa0, p0, a, 0, 0, 0);
      a = __builtin_amdgcn_mfma_f32_16x16x32_bf16(qa1, p1, a, 0, 0, 0);
      b1a[f] = a;
    }
  }
  // bias2 = pq_win @ K^T : wave w owns row-frags {w, w+4} (if < F)
  f32x4 b2a[2][4] = {};
#pragma unroll
  for (int g = 0; g < 2; ++g) {
    int fr = w + g * 4;
    if (fr < F) {
      bf16x8 a0 = *(const bf16x8*)(&U2[fr * 16 + lr][kg * 8]);
      bf16x8 a1 = *(const bf16x8*)(&U2[fr * 16 + lr][kg * 8 + 32]);
#pragma unroll
      for (int nf = 0; nf < 4; ++nf) {
        bf16x8 kb0 = *(const bf16x8*)(&ks[nf * 16 + lr][kg * 8]);
        bf16x8 kb1 = *(const bf16x8*)(&ks[nf * 16 + lr][kg * 8 + 32]);
        f32x4 a = {};
        a = __builtin_amdgcn_mfma_f32_16x16x32_bf16(a0, kb0, a, 0, 0, 0);
        a = __builtin_amdgcn_mfma_f32_16x16x32_bf16(a1, kb1, a, 0, 0, 0);
        b2a[g][nf] = a;
      }
    }
  }
  __syncthreads();  // all window reads done -> overwrite with bias tiles
  u16* b1 = &U1[0][0];  // b1 view [64][136]
#pragma unroll
  for (int f = 0; f < 8; ++f) {
    if (f < F) {
#pragma unroll
      for (int r = 0; r < 4; ++r)
        b1[(w * 16 + kg * 4 + r) * 136 + f * 16 + lr] = f2b(b1a[f][r]);
    }
  }
#pragma unroll
  for (int g = 0; g < 2; ++g) {
    int fr = w + g * 4;
    if (fr < F) {
#pragma unroll
      for (int nf = 0; nf < 4; ++nf)
#pragma unroll
        for (int r = 0; r < 4; ++r)
          U2[fr * 16 + kg * 4 + r][nf * 16 + lr] = f2b(b2a[g][nf][r]);
    }
  }
  __syncthreads();  // bias tiles ready (b2 read cross-wave)

  // V fragments direct from global (issued early, consumed after softmax)
  bf16x8 vb[4][2];
#pragma unroll
  for (int nf = 0; nf < 4; ++nf) {
    const u16* vrow = vT + (size_t)z * 32768 + (size_t)(nf * 16 + lr) * 512 + j0;
    vb[nf][0] = *(const bf16x8*)(vrow + kg * 8);
    vb[nf][1] = *(const bf16x8*)(vrow + kg * 8 + 32);
  }

  // gather bias (LDS) + mask + softmax in exp2 domain (single tile)
  const float SC2 = INV_SCALE * 1.4426950408889634f;
  float mi[4], mj[4];
#pragma unroll
  for (int r = 0; r < 4; ++r) mi[r] = mask[b * 512 + i0 + w * 16 + kg * 4 + r];
#pragma unroll
  for (int nf = 0; nf < 4; ++nf) mj[nf] = mask[b * 512 + j0 + nf * 16 + lr];
  float lgv[4][4];
  bool ok[4][4];
  float tmax[4] = {NEGMAX, NEGMAX, NEGMAX, NEGMAX};
  int iloc = w * 16 + kg * 4;
#pragma unroll
  for (int nf = 0; nf < 4; ++nf) {
    int jloc = nf * 16 + lr;
    int relc = i0 + iloc - (j0 + jloc) + 511;
#pragma unroll
    for (int r = 0; r < 4; ++r) {
      int idx = crl16[relc + r] - ib;
      float bias = b2f(b1[(iloc + r) * 136 + idx]) + b2f(U2[idx][jloc]);
      bool o_ = (mi[r] * mj[nf]) > 0.f;
      float v = o_ ? (sc[nf][r] + bias) * SC2 : NEGMAX;
      ok[nf][r] = o_;
      lgv[nf][r] = v;
      tmax[r] = fmaxf(tmax[r], v);
    }
  }
#pragma unroll
  for (int r = 0; r < 4; ++r) {
#pragma unroll
    for (int off = 8; off; off >>= 1) tmax[r] = fmaxf(tmax[r], __shfl_xor(tmax[r], off));
  }
  float tsum[4];
#pragma unroll
  for (int r = 0; r < 4; ++r) {
    float mn = tmax[r];
    float ls = 0.f;
#pragma unroll
    for (int nf = 0; nf < 4; ++nf) {
      float p = ok[nf][r] ? exp2f(lgv[nf][r] - mn) : 0.f;
      lgv[nf][r] = p;
      ls += p;
    }
    tsum[r] = ls;
  }
#pragma unroll
  for (int r = 0; r < 4; ++r) {
#pragma unroll
    for (int off = 8; off; off >>= 1) tsum[r] += __shfl_xor(tsum[r], off);
  }
  // P (C/D layout) -> per-wave rows of ks (wave-local region, no barrier)
#pragma unroll
  for (int nf = 0; nf < 4; ++nf)
#pragma unroll
    for (int r = 0; r < 4; ++r) ks[w * 16 + kg * 4 + r][nf * 16 + lr] = f2b(lgv[nf][r]);
  bf16x8 pa0 = *(const bf16x8*)(&ks[w * 16 + lr][kg * 8]);
  bf16x8 pa1 = *(const bf16x8*)(&ks[w * 16 + lr][kg * 8 + 32]);
  // PV
  f32x4 o[4] = {};
#pragma unroll
  for (int nf = 0; nf < 4; ++nf) {
    o[nf] = __builtin_amdgcn_mfma_f32_16x16x32_bf16(pa0, vb[nf][0], o[nf], 0, 0, 0);
    o[nf] = __builtin_amdgcn_mfma_f32_16x16x32_bf16(pa1, vb[nf][1], o[nf], 0, 0, 0);
  }
  // packed partial write: 32B contiguous per lane
  unsigned int pk[8];
#pragma unroll
  for (int nf = 0; nf < 4; ++nf) {
    pk[nf * 2 + 0] = (unsigned int)f2b(o[nf][0]) | ((unsigned int)f2b(o[nf][1]) << 16);
    pk[nf * 2 + 1] = (unsigned int)f2b(o[nf][2]) | ((unsigned int)f2b(o[nf][3]) << 16);
  }
  size_t base = (((((size_t)js * 64 + z) * 8 + it) * 4 + w) * 64 + l) * 16;
  *(uint4*)(po + base) = make_uint4(pk[0], pk[1], pk[2], pk[3]);
  *(uint4*)(po + base + 8) = make_uint4(pk[4], pk[5], pk[6], pk[7]);
#pragma unroll
  for (int r = 0; r < 4; ++r) {
    if (lr == 0) {
      int i = i0 + w * 16 + kg * 4 + r;
      size_t mb = (((size_t)js * 64 + z) * 512 + i) * 2;
      pms[mb + 0] = tmax[r];   // log2 domain
      pms[mb + 1] = tsum[r];
    }
  }
}

// ---------------------------------------------------------------------------
// Merge 8 j-split partials (packed layout) -> normalized ctx (bf16).
// ---------------------------------------------------------------------------
__global__ __launch_bounds__(256) void merge_kernel(const u16* __restrict__ po,
                                                    const float* __restrict__ pms,
                                                    u16* __restrict__ ctx) {
  int t = threadIdx.x;
  int w_ = t >> 6, d = t & 63;
  int row = blockIdx.x * 4 + w_;  // 0..32767
  int z = row >> 9, i = row & 511;
  int b = z >> 3, h = z & 7;
  int it = i >> 6, ii = i & 63;
  int aw = ii >> 4, akg = (ii >> 2) & 3, ar = ii & 3;
  int alr = d & 15, anf = d >> 4;
  float mv[8], sv[8], m = NEGMAX;
#pragma unroll
  for (int js = 0; js < 8; ++js) {
    size_t mb = (((size_t)js * 64 + z) * 512 + i) * 2;
    mv[js] = pms[mb + 0];
    sv[js] = pms[mb + 1];
    m = fmaxf(m, mv[js]);
  }
  float o = 0.f, s = 0.f;
#pragma unroll
  for (int js = 0; js < 8; ++js) {
    float wgt = (mv[js] <= -1e37f) ? 0.f : exp2f(mv[js] - m);
    size_t pb = (((((size_t)js * 64 + z) * 8 + it) * 4 + aw) * 64 + (akg * 16 + alr)) * 16
                + anf * 4 + ar;
    o += wgt * b2f(po[pb]);
    s += wgt * sv[js];
  }
  float r = (s > 0.f) ? o / s : 0.f;
  ctx[(size_t)(b * 512 + i) * 512 + h * 64 + d] = f2b(r);
}

// ---------------------------------------------------------------------------
// Host launch
// ---------------------------------------------------------------------------
extern "C" void kernel_launch(void* const* d_in, const int* in_sizes, int n_in,
                              void* d_out, int out_size, void* d_ws, size_t ws_size,
                              hipStream_t stream) {
  const float* x       = (const float*)d_in[0];
  const float* mask    = (const float*)d_in[1];
  const float* emb_s   = (const float*)d_in[2];
  const float* emb_b   = (const float*)d_in[3];
  const float* rel_emb = (const float*)d_in[4];
  const float* rel_s   = (const float*)d_in[5];
  const float* rel_b   = (const float*)d_in[6];
  const float* Wq = (const float*)d_in[7];
  const float* bq = (const float*)d_in[8];
  const float* Wk = (const float*)d_in[9];
  const float* bk = (const float*)d_in[10];
  const float* Wv = (const float*)d_in[11];
  const float* bv = (const float*)d_in[12];
  const float* Wo = (const float*)d_in[13];
  const float* bo = (const float*)d_in[14];
  const float* as_ = (const float*)d_in[15];
  const float* ab_ = (const float*)d_in[16];
  const float* Wi = (const float*)d_in[17];
  const float* bi = (const float*)d_in[18];
  const float* Wf = (const float*)d_in[19];
  const float* bf_ = (const float*)d_in[20];
  const float* fs_ = (const float*)d_in[21];
  const float* fb_ = (const float*)d_in[22];
  const float* Wc = (const float*)d_in[23];
  const float* bc = (const float*)d_in[24];
  float* out = (float*)d_out;

  char* p = (char*)d_ws;
  auto alloc = [&](size_t bytes) {
    char* r = p;
    p += (bytes + 255) & ~(size_t)255;
    return r;
  };
  float* hcat = (float*)alloc((size_t)4608 * 512 * 4);
  float* tmpA = (float*)alloc((size_t)4096 * 512 * 4);
  u16* mid  = (u16*)alloc((size_t)4096 * 768 * 2);
  u16* hbf  = (u16*)alloc((size_t)4608 * 512 * 2);
  u16* qkv  = (u16*)alloc((size_t)4608 * 1536 * 2);     // q|k|v (+pq|pk rows)
  u16* vT   = (u16*)alloc((size_t)64 * 64 * 512 * 2);   // [bh][d][j]
  u16* ctxb = (u16*)alloc((size_t)4096 * 512 * 2);
  u16* po   = (u16*)alloc((size_t)8 * 64 * 512 * 64 * 2);   // packed partials
  float* pms = (float*)alloc((size_t)8 * 64 * 512 * 2 * 4); // [js][bh][i][2]
  u16* WtQKV = (u16*)alloc((size_t)3 * 1536 * 512 * 2);
  u16* WtO  = (u16*)alloc((size_t)3 * 512 * 512 * 2);
  u16* WtI  = (u16*)alloc((size_t)3 * 768 * 512 * 2);
  u16* WtF  = (u16*)alloc((size_t)3 * 512 * 768 * 2);
  u16* WtC  = (u16*)alloc((size_t)100 * 512 * 2);
  float* bqkv = (float*)alloc((size_t)3 * 1536 * 4);
  int* crel = (int*)alloc((size_t)1024 * 4);

  tables_kernel<<<22, 256, 0, stream>>>(bq, bk, bv, crel, bqkv);
  wtrans_all<<<dim3(24, 24, 19), 256, 0, stream>>>(Wq, Wk, Wv, Wo, Wi, Wf, Wc,
                                                   WtQKV, WtO, WtI, WtF, WtC);
  ln_kernel<false, true><<<1024, 256, 0, stream>>>(x, nullptr, emb_s, emb_b, mask,
                                                   hcat, hbf, 4096);
  ln_kernel<false, false><<<128, 256, 0, stream>>>(rel_emb, nullptr, rel_s, rel_b, nullptr,
                                                   hcat + (size_t)4096 * 512,
                                                   hbf + (size_t)4096 * 512, 512);

  for (int l = 0; l < 3; ++l) {
    // fused q|k|v (+pq|pk) projection, vT written in epilogue
    gemm128<1, 1, u16><<<dim3(24, 36), 256, 0, stream>>>(
        hbf, WtQKV + (size_t)l * 786432, bqkv + l * 1536, qkv,
        4608, 1536, 512, 512, 512, 1536, vT);
    // fused QK^T + on-the-fly MFMA bias + XSoftmax + PV, 8-way split-j
    attn_fused<<<4096, 256, 0, stream>>>(qkv, vT, mask, crel, po, pms);
    merge_kernel<<<8192, 256, 0, stream>>>(po, pms, ctxb);
    // O proj -> fp32, LN(+h)
    gemm128<1, 0, float><<<dim3(8, 32), 256, 0, stream>>>(
        ctxb, WtO + (size_t)l * 262144, bo + l * 512, tmpA, 4096, 512, 512,
        512, 512, 512, nullptr);
    ln_kernel<true, false><<<1024, 256, 0, stream>>>(tmpA, hcat, as_ + l * 512, ab_ + l * 512,
                                                     nullptr, hcat, hbf, 4096);
    // FFN
    gemm128<2, 0, u16><<<dim3(12, 32), 256, 0, stream>>>(
        hbf, WtI + (size_t)l * 393216, bi + l * 768, mid, 4096, 768, 512,
        512, 512, 768, nullptr);
    gemm128<1, 0, float><<<dim3(8, 32), 256, 0, stream>>>(
        mid, WtF + (size_t)l * 393216, bf_ + l * 512, tmpA, 4096, 512, 768,
        768, 768, 512, nullptr);
    ln_kernel<true, false><<<1024, 256, 0, stream>>>(tmpA, hcat, fs_ + l * 512, fb_ + l * 512,
                                                     nullptr, hcat, hbf, 4096);
  }
  gemm_bf16<1, float><<<dim3(2, 64), 256, 0, stream>>>(
      hbf, WtC, bc, out, 4096, 100, 512, 512, 512, 100);
}

// Round 13
// 451.464 us; speedup vs baseline: 1.7556x; 1.7057x over previous
//
#include <hip/hip_runtime.h>
#include <hip/hip_bf16.h>
#include <math.h>

// B=8, S=512, HID=512, HEADS=8, DH=64, FF=768, NL=3, SPAN=256, MAXP=512, VOCAB=100
#define EPS_LN 1e-7f
#define INV_SCALE 0.072168783648703221f   // 1/sqrt(64*3)
#define NEGMAX -3.402823466e38f

typedef unsigned short u16;
typedef __attribute__((ext_vector_type(8))) short bf16x8;  // 8 bf16 = 4 VGPRs
typedef __attribute__((ext_vector_type(4))) float f32x4;

__device__ __forceinline__ u16 f2b(float f) {
  union { float f; unsigned int u; } v; v.f = f;
  unsigned int r = v.u + 0x7FFFu + ((v.u >> 16) & 1u);
  return (u16)(r >> 16);
}
__device__ __forceinline__ float b2f(u16 u) {
  union { unsigned int u; float f; } v; v.u = ((unsigned int)u) << 16;
  return v.f;
}
__device__ __forceinline__ float gelu_exact(float v) {
  return 0.5f * v * (1.f + erff(v * 0.70710678118654752440f));
}
// DeBERTa log-bucket for a single rel value (bit-exact with table build)
__device__ __forceinline__ int bucket_clip(int rel) {
  int a = (rel < 128 && rel > -128) ? 127 : (rel < 0 ? -rel : rel);
  int bucket;
  if (a <= 128) {
    bucket = rel;
  } else {
    double lp = ceil(log((double)a / 128.0) / log(511.0 / 128.0) * 127.0) + 128.0;
    int l = (int)lp;
    bucket = (rel > 0) ? l : -l;
  }
  int c = bucket + 256;
  return c < 0 ? 0 : (c > 511 ? 511 : c);
}

// ---------------------------------------------------------------------------
// Small tables: crel (1023) + concat bias [3][1536] = bq|bk|bv.
// ---------------------------------------------------------------------------
__global__ __launch_bounds__(256) void tables_kernel(const float* __restrict__ bq,
                                                     const float* __restrict__ bk,
                                                     const float* __restrict__ bv,
                                                     int* __restrict__ crel,
                                                     float* __restrict__ bqkv) {
  int i = blockIdx.x * 256 + threadIdx.x;
  if (i < 1023) crel[i] = bucket_clip(i - 511);
  int j = i - 1024;
  if (j >= 0 && j < 4608) {
    int l = j / 1536, c = j - l * 1536;
    float v = (c < 512) ? bq[l * 512 + c]
                        : (c < 1024) ? bk[l * 512 + c - 512] : bv[l * 512 + c - 1024];
    bqkv[j] = v;
  }
}

// ---------------------------------------------------------------------------
// LayerNorm over 512 cols; writes fp32 master and optional bf16 mirror.
// ---------------------------------------------------------------------------
template <bool RESID, bool MASK>
__global__ __launch_bounds__(256) void ln_kernel(const float* __restrict__ x,
                                                 const float* __restrict__ res,
                                                 const float* __restrict__ gam,
                                                 const float* __restrict__ bet,
                                                 const float* __restrict__ mask,
                                                 float* __restrict__ out,
                                                 u16* __restrict__ outb, int nrows) {
  int w = threadIdx.x >> 6, ln = threadIdx.x & 63;
  int row = blockIdx.x * 4 + w;
  if (row >= nrows) return;
  const float* xr = x + (size_t)row * 512;
  float v[8];
#pragma unroll
  for (int c = 0; c < 2; ++c) {
    float4 a = *(const float4*)(xr + (ln << 3) + (c << 2));
    v[c * 4 + 0] = a.x; v[c * 4 + 1] = a.y; v[c * 4 + 2] = a.z; v[c * 4 + 3] = a.w;
    if (RESID) {
      float4 r4 = *(const float4*)(res + (size_t)row * 512 + (ln << 3) + (c << 2));
      v[c * 4 + 0] += r4.x; v[c * 4 + 1] += r4.y; v[c * 4 + 2] += r4.z; v[c * 4 + 3] += r4.w;
    }
  }
  float sum = 0.f;
#pragma unroll
  for (int c = 0; c < 8; ++c) sum += v[c];
#pragma unroll
  for (int off = 32; off; off >>= 1) sum += __shfl_xor(sum, off);
  float mu = sum * (1.f / 512.f);
  float vs = 0.f;
#pragma unroll
  for (int c = 0; c < 8; ++c) { float d = v[c] - mu; vs += d * d; }
#pragma unroll
  for (int off = 32; off; off >>= 1) vs += __shfl_xor(vs, off);
  float rstd = 1.f / sqrtf(vs * (1.f / 512.f) + EPS_LN);
  float mk = MASK ? mask[row] : 1.f;
  float* orow = out + (size_t)row * 512;
  u16* brow = outb ? outb + (size_t)row * 512 : nullptr;
#pragma unroll
  for (int c = 0; c < 2; ++c) {
    int col = (ln << 3) + (c << 2);
    float o[4];
#pragma unroll
    for (int q = 0; q < 4; ++q)
      o[q] = ((v[c * 4 + q] - mu) * rstd * gam[col + q] + bet[col + q]) * mk;
    *(float4*)(orow + col) = make_float4(o[0], o[1], o[2], o[3]);
    if (brow) {
      ushort4 ob = { f2b(o[0]), f2b(o[1]), f2b(o[2]), f2b(o[3]) };
      *(ushort4*)(brow + col) = ob;
    }
  }
}

// ---------------------------------------------------------------------------
// ALL weight transposes (f32 [K][N] -> bf16 [N][K]) in ONE dispatch.
// job = blockIdx.z: 0-8 QKV(l,part), 9-11 O, 12-14 I, 15-17 F, 18 C.
// ---------------------------------------------------------------------------
__global__ __launch_bounds__(256) void wtrans_all(const float* __restrict__ Wq,
                                                  const float* __restrict__ Wk,
                                                  const float* __restrict__ Wv,
                                                  const float* __restrict__ Wo,
                                                  const float* __restrict__ Wi,
                                                  const float* __restrict__ Wf,
                                                  const float* __restrict__ Wc,
                                                  u16* __restrict__ WtQKV,
                                                  u16* __restrict__ WtO,
                                                  u16* __restrict__ WtI,
                                                  u16* __restrict__ WtF,
                                                  u16* __restrict__ WtC) {
  __shared__ float tl[32][33];
  int job = blockIdx.z;
  const float* W; u16* Wt; int K, N;
  if (job < 9) {
    int l = job / 3, p3 = job % 3;
    W = (p3 == 0 ? Wq : p3 == 1 ? Wk : Wv) + (size_t)l * 262144;
    Wt = WtQKV + (size_t)l * 786432 + (size_t)p3 * 262144;
    K = 512; N = 512;
  } else if (job < 12) {
    int l = job - 9; W = Wo + (size_t)l * 262144; Wt = WtO + (size_t)l * 262144;
    K = 512; N = 512;
  } else if (job < 15) {
    int l = job - 12; W = Wi + (size_t)l * 393216; Wt = WtI + (size_t)l * 393216;
    K = 512; N = 768;
  } else if (job < 18) {
    int l = job - 15; W = Wf + (size_t)l * 393216; Wt = WtF + (size_t)l * 393216;
    K = 768; N = 512;
  } else {
    W = Wc; Wt = WtC; K = 512; N = 100;
  }
  int n0 = blockIdx.x * 32, k0 = blockIdx.y * 32;
  if (n0 >= N || k0 >= K) return;
  int c = threadIdx.x & 31, r8 = threadIdx.x >> 5;
#pragma unroll
  for (int p = 0; p < 4; ++p) {
    int r = r8 + p * 8;
    int k = k0 + r, n = n0 + c;
    tl[r][c] = (k < K && n < N) ? W[(size_t)k * N + n] : 0.f;
  }
  __syncthreads();
#pragma unroll
  for (int p = 0; p < 4; ++p) {
    int r = r8 + p * 8;
    int n = n0 + r, k = k0 + c;
    if (n < N && k < K) Wt[(size_t)n * K + k] = f2b(tl[c][r]);
  }
}

// ---------------------------------------------------------------------------
// 128x64-tile bf16 MFMA GEMM: C[M,N] = A[M,K] @ B[N,K]^T (+bias, +gelu).
// VT=1 (QKV use): cols >= 1024 (v block) additionally written TRANSPOSED to
// vT [z=b*8+h][d][j] (vtrans fused into epilogue).
// ---------------------------------------------------------------------------
template <int EPI, int VT, typename CT>
__global__ __launch_bounds__(256) void gemm128(const u16* __restrict__ A,
                                               const u16* __restrict__ B,
                                               const float* __restrict__ bias,
                                               CT* __restrict__ C,
                                               int M, int N, int K,
                                               int lda, int ldb, int ldc,
                                               u16* __restrict__ vTout) {
  __shared__ u16 As[128][72];
  __shared__ u16 Bs[64][72];
  int t = threadIdx.x;
  int m0 = blockIdx.y * 128, n0 = blockIdx.x * 64;
  int w = t >> 6, l = t & 63;
  int wr = w >> 1, wc = w & 1, lr = l & 15, kg = l >> 4;
  f32x4 acc[4][2] = {};
  for (int k0 = 0; k0 < K; k0 += 64) {
#pragma unroll
    for (int p = 0; p < 4; ++p) {
      int c = t + (p << 8);
      int row = c >> 3, q = c & 7;
      *(uint4*)(&As[row][q * 8]) =
          *(const uint4*)(A + (size_t)(m0 + row) * lda + k0 + q * 8);
    }
#pragma unroll
    for (int p = 0; p < 2; ++p) {
      int c = t + (p << 8);
      int row = c >> 3, q = c & 7;
      *(uint4*)(&Bs[row][q * 8]) =
          *(const uint4*)(B + (size_t)(n0 + row) * ldb + k0 + q * 8);
    }
    __syncthreads();
#pragma unroll
    for (int s = 0; s < 2; ++s) {
      bf16x8 a[4], bb[2];
#pragma unroll
      for (int m = 0; m < 4; ++m)
        a[m] = *(const bf16x8*)(&As[wr * 64 + m * 16 + lr][kg * 8 + s * 32]);
#pragma unroll
      for (int n = 0; n < 2; ++n)
        bb[n] = *(const bf16x8*)(&Bs[wc * 32 + n * 16 + lr][kg * 8 + s * 32]);
#pragma unroll
      for (int m = 0; m < 4; ++m)
#pragma unroll
        for (int n = 0; n < 2; ++n)
          acc[m][n] = __builtin_amdgcn_mfma_f32_16x16x32_bf16(a[m], bb[n], acc[m][n], 0, 0, 0);
    }
    __syncthreads();
  }
#pragma unroll
  for (int m = 0; m < 4; ++m)
#pragma unroll
    for (int n = 0; n < 2; ++n) {
      int col = n0 + wc * 32 + n * 16 + lr;
      float bv = (EPI >= 1) ? bias[col] : 0.f;
      int rowb = m0 + wr * 64 + m * 16 + kg * 4;
      float vv[4];
#pragma unroll
      for (int r = 0; r < 4; ++r) {
        float v = acc[m][n][r] + bv;
        if (EPI == 2) v = gelu_exact(v);
        vv[r] = v;
        if constexpr (sizeof(CT) == 2) {
          ((u16*)C)[(size_t)(rowb + r) * ldc + col] = f2b(v);
        } else {
          ((float*)C)[(size_t)(rowb + r) * ldc + col] = v;
        }
      }
      if (VT) {
        if (col >= 1024 && rowb < 4096) {
          int zz = (rowb >> 9) * 8 + ((col - 1024) >> 6);
          int dd = (col - 1024) & 63;
          ushort4 o4 = { f2b(vv[0]), f2b(vv[1]), f2b(vv[2]), f2b(vv[3]) };
          *(ushort4*)(vTout + (size_t)zz * 32768 + (size_t)dd * 512 + (rowb & 511)) = o4;
        }
      }
    }
}

// ---------------------------------------------------------------------------
// 64x64-tile bf16 MFMA GEMM (classifier only).
// ---------------------------------------------------------------------------
template <int EPI, typename CT>
__global__ __launch_bounds__(256) void gemm_bf16(const u16* __restrict__ A,
                                                 const u16* __restrict__ B,
                                                 const float* __restrict__ bias,
                                                 CT* __restrict__ C,
                                                 int M, int N, int K,
                                                 int lda, int ldb, int ldc) {
  __shared__ u16 As[64][72];
  __shared__ u16 Bs[64][72];
  int t = threadIdx.x;
  int m0 = blockIdx.y * 64, n0 = blockIdx.x * 64;
  int w = t >> 6, l = t & 63;
  int wr = w >> 1, wc = w & 1, lr = l & 15, kg = l >> 4;
  f32x4 acc[2][2] = {};
  for (int k0 = 0; k0 < K; k0 += 64) {
#pragma unroll
    for (int p = 0; p < 2; ++p) {
      int c = t + (p << 8);
      int row = c >> 3, q = c & 7;
      uint4 av = *(const uint4*)(A + (size_t)(m0 + row) * lda + k0 + q * 8);
      *(uint4*)(&As[row][q * 8]) = av;
      uint4 bv = make_uint4(0u, 0u, 0u, 0u);
      if (n0 + row < N) bv = *(const uint4*)(B + (size_t)(n0 + row) * ldb + k0 + q * 8);
      *(uint4*)(&Bs[row][q * 8]) = bv;
    }
    __syncthreads();
#pragma unroll
    for (int s = 0; s < 2; ++s) {
      bf16x8 a0 = *(const bf16x8*)(&As[wr * 32 + lr][kg * 8 + s * 32]);
      bf16x8 a1 = *(const bf16x8*)(&As[wr * 32 + 16 + lr][kg * 8 + s * 32]);
      bf16x8 b0 = *(const bf16x8*)(&Bs[wc * 32 + lr][kg * 8 + s * 32]);
      bf16x8 b1 = *(const bf16x8*)(&Bs[wc * 32 + 16 + lr][kg * 8 + s * 32]);
      acc[0][0] = __builtin_amdgcn_mfma_f32_16x16x32_bf16(a0, b0, acc[0][0], 0, 0, 0);
      acc[0][1] = __builtin_amdgcn_mfma_f32_16x16x32_bf16(a0, b1, acc[0][1], 0, 0, 0);
      acc[1][0] = __builtin_amdgcn_mfma_f32_16x16x32_bf16(a1, b0, acc[1][0], 0, 0, 0);
      acc[1][1] = __builtin_amdgcn_mfma_f32_16x16x32_bf16(a1, b1, acc[1][1], 0, 0, 0);
    }
    __syncthreads();
  }
#pragma unroll
  for (int m = 0; m < 2; ++m)
#pragma unroll
    for (int n = 0; n < 2; ++n) {
      int col = n0 + wc * 32 + n * 16 + lr;
      if (col < N) {
        float bv = (EPI >= 1) ? bias[col] : 0.f;
#pragma unroll
        for (int r = 0; r < 4; ++r) {
          int row = m0 + wr * 32 + m * 16 + kg * 4 + r;
          float v = acc[m][n][r] + bv;
          if (EPI == 2) v = gelu_exact(v);
          if constexpr (sizeof(CT) == 2) {
            ((u16*)C)[(size_t)row * ldc + col] = f2b(v);
          } else {
            ((float*)C)[(size_t)row * ldc + col] = v;
          }
        }
      }
    }
}

// ---------------------------------------------------------------------------
// Fused disentangled attention, 8-way split-j, bias on-the-fly via MFMA.
// ROUND-10 VERBATIM register structure (84 VGPR measured): unconditional
// 8-frag bias MFMAs, K staged in LDS, analytic ib, unpacked po writes.
// XCD-chunked 1-D grid (wg&7 = xcd) keeps per-XCD working set L2-resident.
// ---------------------------------------------------------------------------
__global__ __launch_bounds__(256) void attn_fused(const u16* __restrict__ qkv,
                                                  const u16* __restrict__ vT,
                                                  const float* __restrict__ mask,
                                                  const int* __restrict__ crel,
                                                  u16* __restrict__ po,
                                                  float* __restrict__ pms) {
  __shared__ u16 ks[64][72];      //  9216 B (K tile; later per-wave P buffer)
  __shared__ u16 U1[128][72];     // 18432 B (pk window -> b1 view [64][136])
  __shared__ u16 U2[128][72];     // 18432 B (pq window -> b2 [128][72])
  __shared__ u16 crl16[1024];     //  2048 B   -> 48128 B total
  int t = threadIdx.x;
  int wg = blockIdx.x;            // 0..4095
  int xcd = wg & 7, qq = wg >> 3;
  int z = xcd * 8 + (qq >> 6);    // b*8+h, chunked per XCD
  int rem = qq & 63;
  int it = rem >> 3, js = rem & 7;
  int b = z >> 3, h = z & 7;
  int i0 = it * 64, j0 = js * 64;
  int w = t >> 6, l = t & 63;
  int lr = l & 15, kg = l >> 4;

  int ib = bucket_clip(i0 - j0 - 63);  // min bucket over tile (crel monotone)

  for (int c = t; c < 1023; c += 256) crl16[c] = (u16)crel[c];
  // stage K tile + pk/pq windows (clamped rows; clamped values never gathered)
  for (int c = t; c < 512; c += 256) {
    int row = c >> 3, off = (c & 7) * 8;
    *(uint4*)(&ks[row][off]) =
        *(const uint4*)(qkv + (size_t)(b * 512 + j0 + row) * 1536 + 512 + h * 64 + off);
  }
  for (int c = t; c < 1024; c += 256) {
    int row = c >> 3, off = (c & 7) * 8;
    int rw = ib + row;
    rw = rw > 511 ? 511 : rw;
    const u16* relrow = qkv + (size_t)(4096 + rw) * 1536 + h * 64;
    *(uint4*)(&U1[row][off]) = *(const uint4*)(relrow + 512 + off);  // pk
    *(uint4*)(&U2[row][off]) = *(const uint4*)(relrow + off);        // pq
  }

  // q fragments straight from global
  const u16* qrow = qkv + (size_t)(b * 512 + i0 + w * 16 + lr) * 1536 + h * 64;
  bf16x8 qa0 = *(const bf16x8*)(qrow + kg * 8);
  bf16x8 qa1 = *(const bf16x8*)(qrow + kg * 8 + 32);
  __syncthreads();

  // QK^T scores (4 col-frags)
  f32x4 sc[4];
#pragma unroll
  for (int nf = 0; nf < 4; ++nf) {
    bf16x8 kb0 = *(const bf16x8*)(&ks[nf * 16 + lr][kg * 8]);
    bf16x8 kb1 = *(const bf16x8*)(&ks[nf * 16 + lr][kg * 8 + 32]);
    f32x4 a = {};
    a = __builtin_amdgcn_mfma_f32_16x16x32_bf16(qa0, kb0, a, 0, 0, 0);
    a = __builtin_amdgcn_mfma_f32_16x16x32_bf16(qa1, kb1, a, 0, 0, 0);
    sc[nf] = a;
  }
  // bias1 = Q @ pk_win^T : wave w owns i-rows w*16..+16, all 128 w-cols
  f32x4 b1a[8];
#pragma unroll
  for (int f = 0; f < 8; ++f) {
    bf16x8 p0 = *(const bf16x8*)(&U1[f * 16 + lr][kg * 8]);
    bf16x8 p1 = *(const bf16x8*)(&U1[f * 16 + lr][kg * 8 + 32]);
    f32x4 a = {};
    a = __builtin_amdgcn_mfma_f32_16x16x32_bf16(qa0, p0, a, 0, 0, 0);
    a = __builtin_amdgcn_mfma_f32_16x16x32_bf16(qa1, p1, a, 0, 0, 0);
    b1a[f] = a;
  }
  // bias2 = pq_win @ K^T : wave w owns bucket-rows w*32..+32 (2 groups of 16)
  f32x4 b2a[2][4];
#pragma unroll
  for (int g = 0; g < 2; ++g) {
    bf16x8 a0 = *(const bf16x8*)(&U2[w * 32 + g * 16 + lr][kg * 8]);
    bf16x8 a1 = *(const bf16x8*)(&U2[w * 32 + g * 16 + lr][kg * 8 + 32]);
#pragma unroll
    for (int f = 0; f < 4; ++f) {
      bf16x8 kb0 = *(const bf16x8*)(&ks[f * 16 + lr][kg * 8]);
      bf16x8 kb1 = *(const bf16x8*)(&ks[f * 16 + lr][kg * 8 + 32]);
      f32x4 a = {};
      a = __builtin_amdgcn_mfma_f32_16x16x32_bf16(a0, kb0, a, 0, 0, 0);
      a = __builtin_amdgcn_mfma_f32_16x16x32_bf16(a1, kb1, a, 0, 0, 0);
      b2a[g][f] = a;
    }
  }
  __syncthreads();  // all reads of U1/U2 done -> overwrite with bias tiles
  u16* b1 = &U1[0][0];  // b1 view [64][136]
#pragma unroll
  for (int f = 0; f < 8; ++f)
#pragma unroll
    for (int r = 0; r < 4; ++r)
      b1[(w * 16 + kg * 4 + r) * 136 + f * 16 + lr] = f2b(b1a[f][r]);
#pragma unroll
  for (int g = 0; g < 2; ++g)
#pragma unroll
    for (int f = 0; f < 4; ++f)
#pragma unroll
      for (int r = 0; r < 4; ++r)
        U2[w * 32 + g * 16 + kg * 4 + r][f * 16 + lr] = f2b(b2a[g][f][r]);
  __syncthreads();  // b2s is read cross-wave

  // V fragments direct from global (issue early, consumed after softmax)
  bf16x8 vb[4][2];
#pragma unroll
  for (int nf = 0; nf < 4; ++nf) {
    const u16* vrow = vT + (size_t)z * 32768 + (size_t)(nf * 16 + lr) * 512 + j0;
    vb[nf][0] = *(const bf16x8*)(vrow + kg * 8);
    vb[nf][1] = *(const bf16x8*)(vrow + kg * 8 + 32);
  }

  // gather bias (both LDS) + mask + softmax (single tile: no rescale)
  float mi[4], mj[4];
#pragma unroll
  for (int r = 0; r < 4; ++r) mi[r] = mask[b * 512 + i0 + w * 16 + kg * 4 + r];
#pragma unroll
  for (int nf = 0; nf < 4; ++nf) mj[nf] = mask[b * 512 + j0 + nf * 16 + lr];
  float lgv[4][4];
  bool ok[4][4];
  float tmax[4] = {NEGMAX, NEGMAX, NEGMAX, NEGMAX};
  int iloc = w * 16 + kg * 4;
#pragma unroll
  for (int nf = 0; nf < 4; ++nf) {
    int jloc = nf * 16 + lr;
    int relc = i0 + iloc - (j0 + jloc) + 511;
#pragma unroll
    for (int r = 0; r < 4; ++r) {
      int idx = crl16[relc + r] - ib;
      float bias = b2f(b1[(iloc + r) * 136 + idx]) + b2f(U2[idx][jloc]);
      bool o_ = (mi[r] * mj[nf]) > 0.f;
      float v = o_ ? (sc[nf][r] + bias) * INV_SCALE : NEGMAX;
      ok[nf][r] = o_;
      lgv[nf][r] = v;
      tmax[r] = fmaxf(tmax[r], v);
    }
  }
#pragma unroll
  for (int r = 0; r < 4; ++r) {
#pragma unroll
    for (int off = 8; off; off >>= 1) tmax[r] = fmaxf(tmax[r], __shfl_xor(tmax[r], off));
  }
  float tsum[4];
#pragma unroll
  for (int r = 0; r < 4; ++r) {
    float mn = tmax[r];
    float ls = 0.f;
#pragma unroll
    for (int nf = 0; nf < 4; ++nf) {
      float p = ok[nf][r] ? __expf(lgv[nf][r] - mn) : 0.f;
      lgv[nf][r] = p;
      ls += p;
    }
    tsum[r] = ls;
  }
#pragma unroll
  for (int r = 0; r < 4; ++r) {
#pragma unroll
    for (int off = 8; off; off >>= 1) tsum[r] += __shfl_xor(tsum[r], off);
  }
  // P (C/D layout) -> per-wave rows of ks (wave-local, no barrier needed)
#pragma unroll
  for (int nf = 0; nf < 4; ++nf)
#pragma unroll
    for (int r = 0; r < 4; ++r) ks[w * 16 + kg * 4 + r][nf * 16 + lr] = f2b(lgv[nf][r]);
  bf16x8 pa0 = *(const bf16x8*)(&ks[w * 16 + lr][kg * 8]);
  bf16x8 pa1 = *(const bf16x8*)(&ks[w * 16 + lr][kg * 8 + 32]);
  // PV
  f32x4 o[4] = {};
#pragma unroll
  for (int nf = 0; nf < 4; ++nf) {
    o[nf] = __builtin_amdgcn_mfma_f32_16x16x32_bf16(pa0, vb[nf][0], o[nf], 0, 0, 0);
    o[nf] = __builtin_amdgcn_mfma_f32_16x16x32_bf16(pa1, vb[nf][1], o[nf], 0, 0, 0);
  }
  // write unnormalized partials
#pragma unroll
  for (int r = 0; r < 4; ++r) {
    int i = i0 + w * 16 + kg * 4 + r;
    size_t pb = (((size_t)js * 64 + z) * 512 + i) * 64;
#pragma unroll
    for (int nf = 0; nf < 4; ++nf) po[pb + nf * 16 + lr] = f2b(o[nf][r]);
    if (lr == 0) {
      size_t mb = (((size_t)js * 64 + z) * 512 + i) * 2;
      pms[mb + 0] = tmax[r];
      pms[mb + 1] = tsum[r];
    }
  }
}

// ---------------------------------------------------------------------------
// Merge 8 j-split partials -> normalized ctx (bf16).
// ---------------------------------------------------------------------------
__global__ __launch_bounds__(256) void merge_kernel(const u16* __restrict__ po,
                                                    const float* __restrict__ pms,
                                                    u16* __restrict__ ctx) {
  int t = threadIdx.x;
  int w = t >> 6, d = t & 63;
  int row = blockIdx.x * 4 + w;   // 0..32767
  int z = row >> 9, i = row & 511;
  int b = z >> 3, h = z & 7;
  float mv[8], sv[8], m = NEGMAX;
#pragma unroll
  for (int js = 0; js < 8; ++js) {
    size_t mb = (((size_t)js * 64 + z) * 512 + i) * 2;
    mv[js] = pms[mb + 0];
    sv[js] = pms[mb + 1];
    m = fmaxf(m, mv[js]);
  }
  float o = 0.f, s = 0.f;
#pragma unroll
  for (int js = 0; js < 8; ++js) {
    float wgt = (mv[js] <= -1e37f) ? 0.f : __expf(mv[js] - m);
    o += wgt * b2f(po[(((size_t)js * 64 + z) * 512 + i) * 64 + d]);
    s += wgt * sv[js];
  }
  float r = (s > 0.f) ? o / s : 0.f;
  ctx[(size_t)(b * 512 + i) * 512 + h * 64 + d] = f2b(r);
}

// ---------------------------------------------------------------------------
// Host launch
// ---------------------------------------------------------------------------
extern "C" void kernel_launch(void* const* d_in, const int* in_sizes, int n_in,
                              void* d_out, int out_size, void* d_ws, size_t ws_size,
                              hipStream_t stream) {
  const float* x       = (const float*)d_in[0];
  const float* mask    = (const float*)d_in[1];
  const float* emb_s   = (const float*)d_in[2];
  const float* emb_b   = (const float*)d_in[3];
  const float* rel_emb = (const float*)d_in[4];
  const float* rel_s   = (const float*)d_in[5];
  const float* rel_b   = (const float*)d_in[6];
  const float* Wq = (const float*)d_in[7];
  const float* bq = (const float*)d_in[8];
  const float* Wk = (const float*)d_in[9];
  const float* bk = (const float*)d_in[10];
  const float* Wv = (const float*)d_in[11];
  const float* bv = (const float*)d_in[12];
  const float* Wo = (const float*)d_in[13];
  const float* bo = (const float*)d_in[14];
  const float* as_ = (const float*)d_in[15];
  const float* ab_ = (const float*)d_in[16];
  const float* Wi = (const float*)d_in[17];
  const float* bi = (const float*)d_in[18];
  const float* Wf = (const float*)d_in[19];
  const float* bf_ = (const float*)d_in[20];
  const float* fs_ = (const float*)d_in[21];
  const float* fb_ = (const float*)d_in[22];
  const float* Wc = (const float*)d_in[23];
  const float* bc = (const float*)d_in[24];
  float* out = (float*)d_out;

  char* p = (char*)d_ws;
  auto alloc = [&](size_t bytes) {
    char* r = p;
    p += (bytes + 255) & ~(size_t)255;
    return r;
  };
  float* hcat = (float*)alloc((size_t)4608 * 512 * 4);
  float* tmpA = (float*)alloc((size_t)4096 * 512 * 4);
  u16* mid  = (u16*)alloc((size_t)4096 * 768 * 2);
  u16* hbf  = (u16*)alloc((size_t)4608 * 512 * 2);
  u16* qkv  = (u16*)alloc((size_t)4608 * 1536 * 2);     // q|k|v (+pq|pk rows)
  u16* vT   = (u16*)alloc((size_t)64 * 64 * 512 * 2);   // [bh][d][j]
  u16* ctxb = (u16*)alloc((size_t)4096 * 512 * 2);
  u16* po   = (u16*)alloc((size_t)8 * 64 * 512 * 64 * 2);   // [js][bh][i][d]
  float* pms = (float*)alloc((size_t)8 * 64 * 512 * 2 * 4); // [js][bh][i][2]
  u16* WtQKV = (u16*)alloc((size_t)3 * 1536 * 512 * 2);
  u16* WtO  = (u16*)alloc((size_t)3 * 512 * 512 * 2);
  u16* WtI  = (u16*)alloc((size_t)3 * 768 * 512 * 2);
  u16* WtF  = (u16*)alloc((size_t)3 * 512 * 768 * 2);
  u16* WtC  = (u16*)alloc((size_t)100 * 512 * 2);
  float* bqkv = (float*)alloc((size_t)3 * 1536 * 4);
  int* crel = (int*)alloc((size_t)1024 * 4);

  tables_kernel<<<22, 256, 0, stream>>>(bq, bk, bv, crel, bqkv);
  wtrans_all<<<dim3(24, 24, 19), 256, 0, stream>>>(Wq, Wk, Wv, Wo, Wi, Wf, Wc,
                                                   WtQKV, WtO, WtI, WtF, WtC);
  ln_kernel<false, true><<<1024, 256, 0, stream>>>(x, nullptr, emb_s, emb_b, mask,
                                                   hcat, hbf, 4096);
  ln_kernel<false, false><<<128, 256, 0, stream>>>(rel_emb, nullptr, rel_s, rel_b, nullptr,
                                                   hcat + (size_t)4096 * 512,
                                                   hbf + (size_t)4096 * 512, 512);

  for (int l = 0; l < 3; ++l) {
    // fused q|k|v (+pq|pk) projection, vT written in epilogue
    gemm128<1, 1, u16><<<dim3(24, 36), 256, 0, stream>>>(
        hbf, WtQKV + (size_t)l * 786432, bqkv + l * 1536, qkv,
        4608, 1536, 512, 512, 512, 1536, vT);
    // fused QK^T + on-the-fly MFMA bias + XSoftmax + PV, 8-way split-j
    attn_fused<<<4096, 256, 0, stream>>>(qkv, vT, mask, crel, po, pms);
    merge_kernel<<<8192, 256, 0, stream>>>(po, pms, ctxb);
    // O proj -> fp32, LN(+h)
    gemm128<1, 0, float><<<dim3(8, 32), 256, 0, stream>>>(
        ctxb, WtO + (size_t)l * 262144, bo + l * 512, tmpA, 4096, 512, 512,
        512, 512, 512, nullptr);
    ln_kernel<true, false><<<1024, 256, 0, stream>>>(tmpA, hcat, as_ + l * 512, ab_ + l * 512,
                                                     nullptr, hcat, hbf, 4096);
    // FFN
    gemm128<2, 0, u16><<<dim3(12, 32), 256, 0, stream>>>(
        hbf, WtI + (size_t)l * 393216, bi + l * 768, mid, 4096, 768, 512,
        512, 512, 768, nullptr);
    gemm128<1, 0, float><<<dim3(8, 32), 256, 0, stream>>>(
        mid, WtF + (size_t)l * 393216, bf_ + l * 512, tmpA, 4096, 512, 768,
        768, 768, 512, nullptr);
    ln_kernel<true, false><<<1024, 256, 0, stream>>>(tmpA, hcat, fs_ + l * 512, fb_ + l * 512,
                                                     nullptr, hcat, hbf, 4096);
  }
  gemm_bf16<1, float><<<dim3(2, 64), 256, 0, stream>>>(
      hbf, WtC, bc, out, 4096, 100, 512, 512, 512, 100);
}